// Round 6
// baseline (25.862 us; speedup 1.0000x reference)
//
#include <hip/hip_runtime.h>

// Warp_Object bicubic warp: B=4, C=3, H=512, W=512, float32.
// Round 6: LDS-staged tiles. Diagnosis: rounds 2/4/5 all ~4.6 CU-cyc/px ==
// L1 line-touch bound on divergent dwordx4 gathers (~70 lines/inst).
// Fix: stage a full-width row band (TH=4 out rows + dy halo -> 23 rows,
// stride 516 floats) into LDS coalesced, stencil-read from LDS. Gaussian-dy
// escapees (|dy|>8, P~1e-7) take a per-px global fallback (always correct).

constexpr int B = 4, C = 3, H = 512, W = 512;
constexpr int HW = H * W;              // 2^18
constexpr int TH = 4;                  // output rows per block
constexpr int HALO_UP = 9, HALO_DN = 10;
constexpr int RS = TH + HALO_UP + HALO_DN;   // 23 staged rows
constexpr int STRIDE = 516;            // %4==0 -> 16B rows; %32==4 -> bank rotate
constexpr int PPT = 8;                 // px per thread (one thread = 8 consecutive x)
constexpr int NB = B * C * (H / TH);   // 1536 blocks

typedef float f4 __attribute__((ext_vector_type(4)));
typedef f4 f4u __attribute__((aligned(4)));   // 4B-aligned float4 load

__global__ __launch_bounds__(256)
void warp_bicubic_lds(const float* __restrict__ img,
                      const float* __restrict__ dxp,
                      const float* __restrict__ dyp,
                      float* __restrict__ out)
{
    __shared__ float tile[RS * STRIDE];        // 47,472 B -> 3 blocks/CU

    int b   = blockIdx.x;
    int swz = (b & 7) * (NB / 8) + (b >> 3);   // XCD-chunked, bijective (1536=8*192)
    int k    = swz >> 7;                       // plane b*C+c
    int band = swz & 127;
    int yb   = band * TH;
    int bd   = k & 3;                          // displacement batch = k % 4

    int tid = threadIdx.x;
    int p0  = tid * PPT;                       // local px index in 4x512 tile
    int ry  = p0 >> 9;                         // 0..3
    int y   = yb + ry;
    int xb  = p0 & (W - 1);                    // multiple of 8

    const float* __restrict__ plane = img + (size_t)k * HW;

    // displacement loads issued early; latency overlaps staging
    const f4 dxlo = *(const f4*)(dxp + bd * HW + y * W + xb);
    const f4 dxhi = *(const f4*)(dxp + bd * HW + y * W + xb + 4);
    const f4 dylo = *(const f4*)(dyp + bd * HW + y * W + xb);
    const f4 dyhi = *(const f4*)(dyp + bd * HW + y * W + xb + 4);

    // cooperative coalesced staging: RS rows x 512 floats as f4 chunks
    for (int c = tid; c < RS * 128; c += 256) {
        int r   = c >> 7;
        int col = (c & 127) << 2;
        int sr  = min(max(yb - HALO_UP + r, 0), H - 1);   // clamp-to-edge source
        f4 v = *(const f4*)(plane + sr * W + col);
        *(f4*)&tile[r * STRIDE + col] = v;                // 16B-aligned ds_write
    }
    __syncthreads();

    const float dxa[8] = {dxlo.x, dxlo.y, dxlo.z, dxlo.w,
                          dxhi.x, dxhi.y, dxhi.z, dxhi.w};
    const float dya[8] = {dylo.x, dylo.y, dylo.z, dylo.w,
                          dyhi.x, dyhi.y, dyhi.z, dyhi.w};

    float res[PPT];
#pragma unroll
    for (int p = 0; p < PPT; ++p) {
        float xm = (float)(xb + p) + dxa[p];   // == ref up to ~3e-5 px rounding
        float ym = (float)y + dya[p];
        float x0f = floorf(xm), y0f = floorf(ym);
        float tx = xm - x0f, ty = ym - y0f;
        int x0 = (int)x0f, y0 = (int)y0f;
        int s  = min(max(x0 - 1, 0), W - 4);   // 4-wide window, always in-row

        float tx2 = tx * tx, tx3 = tx2 * tx;
        float cx0 = (-tx3 + 2.0f * tx2 - tx) * 0.5f;
        float cx1 = (3.0f * tx3 - 5.0f * tx2 + 2.0f) * 0.5f;
        float cx2 = (-3.0f * tx3 + 4.0f * tx2 + tx) * 0.5f;
        float cx3 = 1.0f - (cx0 + cx1 + cx2);

        float ty2 = ty * ty, ty3 = ty2 * ty;
        float cy[4];
        cy[0] = (-ty3 + 2.0f * ty2 - ty) * 0.5f;
        cy[1] = (3.0f * ty3 - 5.0f * ty2 + 2.0f) * 0.5f;
        cy[2] = (-3.0f * ty3 + 4.0f * ty2 + ty) * 0.5f;
        cy[3] = 1.0f - (cy[0] + cy[1] + cy[2]);

        float w0, w1, w2, w3;
        if (x0 >= 1 && x0 <= W - 3) {          // interior: weights = cx
            w0 = cx0; w1 = cx1; w2 = cx2; w3 = cx3;
        } else {                               // fold clamped taps into window
            w0 = w1 = w2 = w3 = 0.f;
            const float cxa[4] = {cx0, cx1, cx2, cx3};
#pragma unroll
            for (int o = 0; o < 4; ++o) {
                int xi = min(max(x0 - 1 + o, 0), W - 1);
                int e  = xi - s;               // 0..3 always
                float c = cxa[o];
                w0 += (e == 0) ? c : 0.f;
                w1 += (e == 1) ? c : 0.f;
                w2 += (e == 2) ? c : 0.f;
                w3 += (e == 3) ? c : 0.f;
            }
        }

        float acc = 0.0f;
        unsigned rel = (unsigned)(y0 - (yb - 8));   // in-tile iff y0 in [yb-8, yb+11]
        if (__builtin_expect(rel <= 19u, 1)) {
            // LDS stencil: staged row of (y0-1) is y0-yb+8 in [0,19]
            int base = (y0 - yb + 8) * STRIDE + s;
#pragma unroll
            for (int j = 0; j < 4; ++j) {
                const float* rp = &tile[base + j * STRIDE];
                acc += cy[j] * (w0 * rp[0] + w1 * rp[1] + w2 * rp[2] + w3 * rp[3]);
            }
        } else {
            // rare Gaussian-tail escape: correct global path
#pragma unroll
            for (int j = 0; j < 4; ++j) {
                int yi = min(max(y0 - 1 + j, 0), H - 1);
                f4 v = *(const f4u*)(plane + yi * W + s);
                acc += cy[j] * (w0 * v.x + w1 * v.y + w2 * v.z + w3 * v.w);
            }
        }
        res[p] = acc;
    }

    f4 r0 = {res[0], res[1], res[2], res[3]};
    f4 r1 = {res[4], res[5], res[6], res[7]};
    float* op = out + (size_t)k * HW + y * W + xb;
    __builtin_nontemporal_store(r0, (f4*)op);
    __builtin_nontemporal_store(r1, (f4*)(op + 4));
}

extern "C" void kernel_launch(void* const* d_in, const int* in_sizes, int n_in,
                              void* d_out, int out_size, void* d_ws, size_t ws_size,
                              hipStream_t stream) {
    const float* img = (const float*)d_in[0];
    const float* dx  = (const float*)d_in[1];
    const float* dy  = (const float*)d_in[2];
    float* out = (float*)d_out;

    dim3 block(256);
    dim3 grid(NB);   // 1536
    hipLaunchKernelGGL(warp_bicubic_lds, grid, block, 0, stream,
                       img, dx, dy, out);
}

// Round 7
// 20.653 us; speedup vs baseline: 1.2522x; 1.2522x over previous
//
#include <hip/hip_runtime.h>

// Warp_Object bicubic warp: B=4, C=3, H=512, W=512, float32.
// Round 7: LDS-staged tiles, conflict-free mapping. Round-6 post-mortem:
// PPT=8-consecutive made lanes stride-8 in x -> LDS banks (4r+s)%32 hit
// ~16-way conflicts. Now: wave = output row, lane l handles x = l+64p
// -> s consecutive across lanes -> ~2 lanes/bank (free). Halo +-6/7 ->
// RS=17 rows, 35KB LDS, 4 blocks/CU; Gaussian-tail escapees (P~4e-4)
// take the always-correct global fallback.

constexpr int B = 4, C = 3, H = 512, W = 512;
constexpr int HW = H * W;              // 2^18
constexpr int TH = 4;                  // output rows per block (1 per wave)
constexpr int HALO_UP = 6, HALO_DN = 7;
constexpr int RS = TH + HALO_UP + HALO_DN;   // 17 staged rows
constexpr int STRIDE = 516;            // 16B-aligned rows; 516%32=4 bank rotate
constexpr int PPT = 8;                 // px per thread, stride-64 in x
constexpr int NB = B * C * (H / TH);   // 1536 blocks

typedef float f4 __attribute__((ext_vector_type(4)));
typedef f4 f4u __attribute__((aligned(4)));   // 4B-aligned float4 load

__global__ __launch_bounds__(256)
void warp_bicubic_lds(const float* __restrict__ img,
                      const float* __restrict__ dxp,
                      const float* __restrict__ dyp,
                      float* __restrict__ out)
{
    __shared__ float tile[RS * STRIDE];        // 35,088 B -> 4 blocks/CU

    int b   = blockIdx.x;
    int swz = (b & 7) * (NB / 8) + (b >> 3);   // XCD-chunked, bijective (1536=8*192)
    int k    = swz >> 7;                       // plane b*C+c
    int band = swz & 127;
    int yb   = band * TH;
    int bd   = k & 3;                          // displacement batch = k % 4

    int tid  = threadIdx.x;
    int ry   = tid >> 6;                       // wave id = row in band
    int lane = tid & 63;
    int y    = yb + ry;

    const float* __restrict__ plane = img + (size_t)k * HW;
    const float* __restrict__ dxr = dxp + bd * HW + y * W + lane;
    const float* __restrict__ dyr = dyp + bd * HW + y * W + lane;

    // displacement loads issued first; latency hides under staging
    float dxa[PPT], dya[PPT];
#pragma unroll
    for (int p = 0; p < PPT; ++p) {
        dxa[p] = __builtin_nontemporal_load(dxr + 64 * p);
        dya[p] = __builtin_nontemporal_load(dyr + 64 * p);
    }

    // cooperative coalesced staging: RS rows x 512 floats as f4 chunks
    for (int c = tid; c < RS * 128; c += 256) {
        int r   = c >> 7;
        int col = (c & 127) << 2;
        int sr  = min(max(yb - HALO_UP + r, 0), H - 1);   // clamp-to-edge
        f4 v = *(const f4*)(plane + sr * W + col);
        *(f4*)&tile[r * STRIDE + col] = v;                // 16B-aligned ds_write
    }
    __syncthreads();

    float* __restrict__ orow = out + (size_t)k * HW + y * W + lane;

#pragma unroll
    for (int p = 0; p < PPT; ++p) {
        int x = lane + 64 * p;
        float xm = (float)x + dxa[p];          // == ref up to ~3e-5 px rounding
        float ym = (float)y + dya[p];
        float x0f = floorf(xm), y0f = floorf(ym);
        float tx = xm - x0f, ty = ym - y0f;
        int x0 = (int)x0f, y0 = (int)y0f;
        int s  = min(max(x0 - 1, 0), W - 4);   // 4-wide window start

        float tx2 = tx * tx, tx3 = tx2 * tx;
        float cx0 = (-tx3 + 2.0f * tx2 - tx) * 0.5f;
        float cx1 = (3.0f * tx3 - 5.0f * tx2 + 2.0f) * 0.5f;
        float cx2 = (-3.0f * tx3 + 4.0f * tx2 + tx) * 0.5f;
        float cx3 = 1.0f - (cx0 + cx1 + cx2);

        float ty2 = ty * ty, ty3 = ty2 * ty;
        float cy0 = (-ty3 + 2.0f * ty2 - ty) * 0.5f;
        float cy1 = (3.0f * ty3 - 5.0f * ty2 + 2.0f) * 0.5f;
        float cy2 = (-3.0f * ty3 + 4.0f * ty2 + ty) * 0.5f;
        float cy3 = 1.0f - (cy0 + cy1 + cy2);

        float w0, w1, w2, w3;
        if (__builtin_expect(x0 >= 1 && x0 <= W - 3, 1)) {   // interior
            w0 = cx0; w1 = cx1; w2 = cx2; w3 = cx3;
        } else {                                // fold clamped taps into window
            w0 = w1 = w2 = w3 = 0.f;
            const float cxa[4] = {cx0, cx1, cx2, cx3};
#pragma unroll
            for (int o = 0; o < 4; ++o) {
                int xi = min(max(x0 - 1 + o, 0), W - 1);
                int e  = xi - s;                // 0..3 always
                float c = cxa[o];
                w0 += (e == 0) ? c : 0.f;
                w1 += (e == 1) ? c : 0.f;
                w2 += (e == 2) ? c : 0.f;
                w3 += (e == 3) ? c : 0.f;
            }
        }

        float acc = 0.0f;
        // in-tile iff y0 in [yb-HALO_UP+1, yb+TH-1+HALO_DN-2] -> rel in [0, RS-4]
        unsigned rel = (unsigned)(y0 - (yb - HALO_UP + 1));
        if (__builtin_expect(rel <= (unsigned)(RS - 4), 1)) {
            // staged row rel holds clamp(y0-1), rel+j holds clamp(y0-1+j)
            const float* rp = &tile[rel * STRIDE + s];
            float r0 = cy0 * (w0 * rp[0] + w1 * rp[1] + w2 * rp[2] + w3 * rp[3]);
            rp += STRIDE;
            float r1 = cy1 * (w0 * rp[0] + w1 * rp[1] + w2 * rp[2] + w3 * rp[3]);
            rp += STRIDE;
            float r2 = cy2 * (w0 * rp[0] + w1 * rp[1] + w2 * rp[2] + w3 * rp[3]);
            rp += STRIDE;
            float r3 = cy3 * (w0 * rp[0] + w1 * rp[1] + w2 * rp[2] + w3 * rp[3]);
            acc = (r0 + r1) + (r2 + r3);
        } else {
            // rare Gaussian-tail escape: correct global path
            const float cya[4] = {cy0, cy1, cy2, cy3};
#pragma unroll
            for (int j = 0; j < 4; ++j) {
                int yi = min(max(y0 - 1 + j, 0), H - 1);
                f4 v = *(const f4u*)(plane + yi * W + s);
                acc += cya[j] * (w0 * v.x + w1 * v.y + w2 * v.z + w3 * v.w);
            }
        }
        __builtin_nontemporal_store(acc, orow + 64 * p);
    }
}

extern "C" void kernel_launch(void* const* d_in, const int* in_sizes, int n_in,
                              void* d_out, int out_size, void* d_ws, size_t ws_size,
                              hipStream_t stream) {
    const float* img = (const float*)d_in[0];
    const float* dx  = (const float*)d_in[1];
    const float* dy  = (const float*)d_in[2];
    float* out = (float*)d_out;

    dim3 block(256);
    dim3 grid(NB);   // 1536
    hipLaunchKernelGGL(warp_bicubic_lds, grid, block, 0, stream,
                       img, dx, dy, out);
}

// Round 8
// 18.489 us; speedup vs baseline: 1.3987x; 1.1170x over previous
//
#include <hip/hip_runtime.h>

// Warp_Object bicubic warp: B=4, C=3, H=512, W=512, float32.
// Round 8: coefficient reuse across channel planes. Quirk: output planes
// {bd, bd+4, bd+8} share displacement batch bd -> identical sampling coords.
// Block = (bd, 4-row band). Loop planes sequentially over ONE 35KB LDS tile:
//   stage plane -> barrier -> stencil (reusing per-position coeffs kept in
//   VGPRs) -> barrier -> restage. Coeff math, dx/dy reads, addressing /3.
// 512 thr/block, 512 blocks = exactly 2 resident blocks/CU (grid co-resident).
// Lane-consecutive x mapping keeps LDS reads ~conflict-free (round-7 layout).

constexpr int B = 4, C = 3, H = 512, W = 512;
constexpr int HW = H * W;              // 2^18
constexpr int TH = 4;                  // output rows per block
constexpr int HALO_UP = 6, HALO_DN = 7;
constexpr int RS = TH + HALO_UP + HALO_DN;   // 17 staged rows
constexpr int STRIDE = 516;            // 16B rows; 516%32=4 bank rotate
constexpr int NPOS = 4;                // positions per thread
constexpr int NT = 512;                // threads per block
constexpr int NB = B * (H / TH);       // 512 blocks

typedef float f4 __attribute__((ext_vector_type(4)));
typedef f4 f4u __attribute__((aligned(4)));   // 4B-aligned float4 load

__global__ __launch_bounds__(NT, 4)
void warp_bicubic_planes(const float* __restrict__ img,
                         const float* __restrict__ dxp,
                         const float* __restrict__ dyp,
                         float* __restrict__ out)
{
    __shared__ float tile[RS * STRIDE];        // 35,088 B

    int b   = blockIdx.x;
    int swz = (b & 7) * (NB / 8) + (b >> 3);   // XCD-chunked, bijective (512=8*64)
    int bd   = swz >> 7;                       // displacement batch 0..3
    int band = swz & 127;
    int yb   = band * TH;

    int tid  = threadIdx.x;
    int wave = tid >> 6;                       // 0..7
    int ry   = wave >> 1;                      // row in band 0..3
    int half = wave & 1;                       // left/right 256 cols
    int lane = tid & 63;
    int y    = yb + ry;
    int xbase = half * 256 + lane;             // x = xbase + 64p

    // ---- phase 0: displacement loads (once per position, /3 planes) ----
    const float* __restrict__ dxr = dxp + bd * HW + y * W + xbase;
    const float* __restrict__ dyr = dyp + bd * HW + y * W + xbase;
    float dxa[NPOS], dya[NPOS];
#pragma unroll
    for (int p = 0; p < NPOS; ++p) {
        dxa[p] = __builtin_nontemporal_load(dxr + 64 * p);
        dya[p] = __builtin_nontemporal_load(dyr + 64 * p);
    }

    // ---- phase 1: per-position coefficients, persisted across planes ----
    float wx[NPOS][4];      // x-weights (clamp folded)
    float cyw[NPOS][4];     // y-coefficients
    int   lbase[NPOS];      // LDS dword base (rel*STRIDE + s), valid if in-tile
    unsigned relv[NPOS];    // in-tile iff relv <= RS-4
    int   sv[NPOS];         // window start (for fallback)
#pragma unroll
    for (int p = 0; p < NPOS; ++p) {
        int x = xbase + 64 * p;
        float xm = (float)x + dxa[p];          // == ref up to ~3e-5 px rounding
        float ym = (float)y + dya[p];
        float x0f = floorf(xm), y0f = floorf(ym);
        float tx = xm - x0f, ty = ym - y0f;
        int x0 = (int)x0f, y0 = (int)y0f;
        int s  = min(max(x0 - 1, 0), W - 4);
        sv[p] = s;

        float tx2 = tx * tx, tx3 = tx2 * tx;
        float cx0 = (-tx3 + 2.0f * tx2 - tx) * 0.5f;
        float cx1 = (3.0f * tx3 - 5.0f * tx2 + 2.0f) * 0.5f;
        float cx2 = (-3.0f * tx3 + 4.0f * tx2 + tx) * 0.5f;
        float cx3 = 1.0f - (cx0 + cx1 + cx2);

        float ty2 = ty * ty, ty3 = ty2 * ty;
        cyw[p][0] = (-ty3 + 2.0f * ty2 - ty) * 0.5f;
        cyw[p][1] = (3.0f * ty3 - 5.0f * ty2 + 2.0f) * 0.5f;
        cyw[p][2] = (-3.0f * ty3 + 4.0f * ty2 + ty) * 0.5f;
        cyw[p][3] = 1.0f - (cyw[p][0] + cyw[p][1] + cyw[p][2]);

        if (__builtin_expect(x0 >= 1 && x0 <= W - 3, 1)) {
            wx[p][0] = cx0; wx[p][1] = cx1; wx[p][2] = cx2; wx[p][3] = cx3;
        } else {
            float w0 = 0.f, w1 = 0.f, w2 = 0.f, w3 = 0.f;
            const float cxa[4] = {cx0, cx1, cx2, cx3};
#pragma unroll
            for (int o = 0; o < 4; ++o) {
                int xi = min(max(x0 - 1 + o, 0), W - 1);
                int e  = xi - s;
                float c = cxa[o];
                w0 += (e == 0) ? c : 0.f;
                w1 += (e == 1) ? c : 0.f;
                w2 += (e == 2) ? c : 0.f;
                w3 += (e == 3) ? c : 0.f;
            }
            wx[p][0] = w0; wx[p][1] = w1; wx[p][2] = w2; wx[p][3] = w3;
        }

        // in-tile iff y0 in [yb-HALO_UP+1, yb+HALO_UP+... ] -> rel in [0, RS-4]
        unsigned rel = (unsigned)(y0 - (yb - HALO_UP + 1));
        relv[p]  = rel;
        lbase[p] = (int)rel * STRIDE + s;
    }

    // ---- plane loop: stage -> stencil, coefficients reused ----
#pragma unroll
    for (int c = 0; c < C; ++c) {
        int kp = bd + 4 * c;                   // output/image plane index
        const float* __restrict__ plane = img + (size_t)kp * HW;

        if (c > 0) __syncthreads();            // all reads of prev tile done
        for (int cc = tid; cc < RS * 128; cc += NT) {
            int r   = cc >> 7;
            int col = (cc & 127) << 2;
            int sr  = min(max(yb - HALO_UP + r, 0), H - 1);   // clamp-to-edge
            *(f4*)&tile[r * STRIDE + col] = *(const f4*)(plane + sr * W + col);
        }
        __syncthreads();

        float* __restrict__ orow = out + (size_t)kp * HW + y * W + xbase;
#pragma unroll
        for (int p = 0; p < NPOS; ++p) {
            float acc;
            if (__builtin_expect(relv[p] <= (unsigned)(RS - 4), 1)) {
                const float* rp = &tile[lbase[p]];
                float r0 = cyw[p][0] * (wx[p][0]*rp[0] + wx[p][1]*rp[1] + wx[p][2]*rp[2] + wx[p][3]*rp[3]);
                rp += STRIDE;
                float r1 = cyw[p][1] * (wx[p][0]*rp[0] + wx[p][1]*rp[1] + wx[p][2]*rp[2] + wx[p][3]*rp[3]);
                rp += STRIDE;
                float r2 = cyw[p][2] * (wx[p][0]*rp[0] + wx[p][1]*rp[1] + wx[p][2]*rp[2] + wx[p][3]*rp[3]);
                rp += STRIDE;
                float r3 = cyw[p][3] * (wx[p][0]*rp[0] + wx[p][1]*rp[1] + wx[p][2]*rp[2] + wx[p][3]*rp[3]);
                acc = (r0 + r1) + (r2 + r3);
            } else {
                // Gaussian-tail escape (P ~ 3e-5/px): correct global path
                int y0 = (int)relv[p] + (yb - HALO_UP + 1);
                acc = 0.f;
#pragma unroll
                for (int j = 0; j < 4; ++j) {
                    int yi = min(max(y0 - 1 + j, 0), H - 1);
                    f4 v = *(const f4u*)(plane + yi * W + sv[p]);
                    acc += cyw[p][j] * (wx[p][0]*v.x + wx[p][1]*v.y + wx[p][2]*v.z + wx[p][3]*v.w);
                }
            }
            __builtin_nontemporal_store(acc, orow + 64 * p);
        }
    }
}

extern "C" void kernel_launch(void* const* d_in, const int* in_sizes, int n_in,
                              void* d_out, int out_size, void* d_ws, size_t ws_size,
                              hipStream_t stream) {
    const float* img = (const float*)d_in[0];
    const float* dx  = (const float*)d_in[1];
    const float* dy  = (const float*)d_in[2];
    float* out = (float*)d_out;

    dim3 block(NT);
    dim3 grid(NB);   // 512 blocks -> 2 resident blocks/CU, whole grid co-resident
    hipLaunchKernelGGL(warp_bicubic_planes, grid, block, 0, stream,
                       img, dx, dy, out);
}

// Round 9
// 17.645 us; speedup vs baseline: 1.4656x; 1.0478x over previous
//
#include <hip/hip_runtime.h>

// Warp_Object bicubic warp: B=4, C=3, H=512, W=512, float32.
// Round 9: occupancy attack. Round-8 budget: no pipe saturated (VALU 0.4,
// LDS 0.8, staging 0.5 cyc/px vs 3.6 measured) -> stall-bound at 4 waves/SIMD.
// Block = (bd, 4-row band, 256-col half): 17x272 tile = 18.5KB, 1024 blocks
// = 4 blocks/CU = 8 waves/SIMD, staged dwords/px 4.25 -> 1.5. Plane loop
// reuses per-position coeffs (round-8 quirk exploit). NPOS=2 -> ~20 VGPR
// persistent, launch_bounds(512,8) caps 64 VGPR. Escapees (P~2e-4 in y,
// ~1e-6 in x) take the always-correct global fallback.

constexpr int B = 4, C = 3, H = 512, W = 512;
constexpr int HW = H * W;              // 2^18
constexpr int TH = 4;                  // output rows per block
constexpr int HALO_UP = 6, HALO_DN = 7;
constexpr int RS = TH + HALO_UP + HALO_DN;   // 17 staged rows
constexpr int LST = 272;               // staged cols; 16B-aligned, %32=16 rotate
constexpr int NPOS = 2;                // positions per thread
constexpr int NT = 512;                // threads per block
constexpr int NB = B * (H / TH) * 2;   // 1024 blocks

typedef float f4 __attribute__((ext_vector_type(4)));
typedef f4 f4u __attribute__((aligned(4)));   // 4B-aligned float4 load

__global__ __launch_bounds__(NT, 8)
void warp_bicubic_xsplit(const float* __restrict__ img,
                         const float* __restrict__ dxp,
                         const float* __restrict__ dyp,
                         float* __restrict__ out)
{
    __shared__ float tile[RS * LST];           // 18,496 B -> 4 blocks/CU (wave-lim)

    int b   = blockIdx.x;
    int swz = (b & 7) * (NB / 8) + (b >> 3);   // XCD-chunked, bijective (1024=8*128)
    int bd   = swz >> 8;                       // displacement batch 0..3
    int band = (swz >> 1) & 127;
    int half = swz & 1;
    int yb   = band * TH;
    int xb   = half * 256;
    int cb   = half ? 248 : 0;                 // first staged image col

    int tid  = threadIdx.x;
    int wave = tid >> 6;                       // 0..7
    int ry   = wave >> 1;                      // row in band 0..3
    int hw   = wave & 1;                       // 128-col subhalf
    int lane = tid & 63;
    int y    = yb + ry;
    int xs   = xb + hw * 128 + lane;           // x = xs + 64p, lanes consecutive
    int pixoff = y * W + xs;

    // ---- phase 0: displacement loads (once, reused across 3 planes) ----
    float dxa[NPOS], dya[NPOS];
#pragma unroll
    for (int p = 0; p < NPOS; ++p) {
        dxa[p] = __builtin_nontemporal_load(dxp + bd * HW + pixoff + 64 * p);
        dya[p] = __builtin_nontemporal_load(dyp + bd * HW + pixoff + 64 * p);
    }

    // ---- phase 1: per-position coefficients, persisted across planes ----
    float wx[NPOS][4];      // x-weights (image-edge clamp folded)
    float cyw[NPOS][4];     // y-coefficients
    unsigned relv[NPOS];    // y in-tile iff relv <= RS-4
    unsigned lsv[NPOS];     // LDS col; x in-tile iff lsv <= LST-4
#pragma unroll
    for (int p = 0; p < NPOS; ++p) {
        int x = xs + 64 * p;
        float xm = (float)x + dxa[p];          // == ref up to ~3e-5 px rounding
        float ym = (float)y + dya[p];
        float x0f = floorf(xm), y0f = floorf(ym);
        float tx = xm - x0f, ty = ym - y0f;
        int x0 = (int)x0f, y0 = (int)y0f;
        int s  = min(max(x0 - 1, 0), W - 4);   // 4-wide window start (image cols)

        float tx2 = tx * tx, tx3 = tx2 * tx;
        float cx0 = (-tx3 + 2.0f * tx2 - tx) * 0.5f;
        float cx1 = (3.0f * tx3 - 5.0f * tx2 + 2.0f) * 0.5f;
        float cx2 = (-3.0f * tx3 + 4.0f * tx2 + tx) * 0.5f;
        float cx3 = 1.0f - (cx0 + cx1 + cx2);

        float ty2 = ty * ty, ty3 = ty2 * ty;
        cyw[p][0] = (-ty3 + 2.0f * ty2 - ty) * 0.5f;
        cyw[p][1] = (3.0f * ty3 - 5.0f * ty2 + 2.0f) * 0.5f;
        cyw[p][2] = (-3.0f * ty3 + 4.0f * ty2 + ty) * 0.5f;
        cyw[p][3] = 1.0f - (cyw[p][0] + cyw[p][1] + cyw[p][2]);

        if (__builtin_expect(x0 >= 1 && x0 <= W - 3, 1)) {
            wx[p][0] = cx0; wx[p][1] = cx1; wx[p][2] = cx2; wx[p][3] = cx3;
        } else {                               // fold image-edge taps into window
            float w0 = 0.f, w1 = 0.f, w2 = 0.f, w3 = 0.f;
            const float cxa[4] = {cx0, cx1, cx2, cx3};
#pragma unroll
            for (int o = 0; o < 4; ++o) {
                int xi = min(max(x0 - 1 + o, 0), W - 1);
                int e  = xi - s;               // 0..3 always
                float c = cxa[o];
                w0 += (e == 0) ? c : 0.f;
                w1 += (e == 1) ? c : 0.f;
                w2 += (e == 2) ? c : 0.f;
                w3 += (e == 3) ? c : 0.f;
            }
            wx[p][0] = w0; wx[p][1] = w1; wx[p][2] = w2; wx[p][3] = w3;
        }

        relv[p] = (unsigned)(y0 - (yb - HALO_UP + 1));   // staged row of y0-1
        lsv[p]  = (unsigned)(s - cb);                    // staged col of window
    }

    // ---- plane loop: stage -> stencil, coefficients reused ----
#pragma unroll
    for (int c = 0; c < C; ++c) {
        int kp = bd + 4 * c;
        const float* __restrict__ plane = img + (size_t)kp * HW;

        if (c > 0) __syncthreads();            // all reads of prev tile done
        for (int cc = tid; cc < RS * (LST / 4); cc += NT) {   // 1156 chunks
            int r   = cc / (LST / 4);
            int c4  = (cc - r * (LST / 4)) * 4;
            int scol = min(cb + c4, W - 4);    // clamp half-1 tail (cols never read)
            int sr   = min(max(yb - HALO_UP + r, 0), H - 1);  // y clamp-to-edge
            *(f4*)&tile[r * LST + c4] = *(const f4*)(plane + sr * W + scol);
        }
        __syncthreads();

        float* __restrict__ obase = out + (size_t)kp * HW + pixoff;
#pragma unroll
        for (int p = 0; p < NPOS; ++p) {
            float acc;
            if (__builtin_expect(relv[p] <= (unsigned)(RS - 4) &&
                                 lsv[p]  <= (unsigned)(LST - 4), 1)) {
                const float* rp = &tile[relv[p] * LST + lsv[p]];
                float r0 = cyw[p][0] * (wx[p][0]*rp[0] + wx[p][1]*rp[1] + wx[p][2]*rp[2] + wx[p][3]*rp[3]);
                rp += LST;
                float r1 = cyw[p][1] * (wx[p][0]*rp[0] + wx[p][1]*rp[1] + wx[p][2]*rp[2] + wx[p][3]*rp[3]);
                rp += LST;
                float r2 = cyw[p][2] * (wx[p][0]*rp[0] + wx[p][1]*rp[1] + wx[p][2]*rp[2] + wx[p][3]*rp[3]);
                rp += LST;
                float r3 = cyw[p][3] * (wx[p][0]*rp[0] + wx[p][1]*rp[1] + wx[p][2]*rp[2] + wx[p][3]*rp[3]);
                acc = (r0 + r1) + (r2 + r3);
            } else {
                // rare escape (Gaussian tail): correct global path
                int y0 = (int)relv[p] + (yb - HALO_UP + 1);
                int s  = (int)lsv[p] + cb;
                acc = 0.f;
#pragma unroll
                for (int j = 0; j < 4; ++j) {
                    int yi = min(max(y0 - 1 + j, 0), H - 1);
                    f4 v = *(const f4u*)(plane + yi * W + s);
                    acc += cyw[p][j] * (wx[p][0]*v.x + wx[p][1]*v.y + wx[p][2]*v.z + wx[p][3]*v.w);
                }
            }
            __builtin_nontemporal_store(acc, obase + 64 * p);
        }
    }
}

extern "C" void kernel_launch(void* const* d_in, const int* in_sizes, int n_in,
                              void* d_out, int out_size, void* d_ws, size_t ws_size,
                              hipStream_t stream) {
    const float* img = (const float*)d_in[0];
    const float* dx  = (const float*)d_in[1];
    const float* dy  = (const float*)d_in[2];
    float* out = (float*)d_out;

    dim3 block(NT);
    dim3 grid(NB);   // 1024 blocks -> 4 resident blocks/CU, whole grid co-resident
    hipLaunchKernelGGL(warp_bicubic_xsplit, grid, block, 0, stream,
                       img, dx, dy, out);
}

// Round 10
// 16.770 us; speedup vs baseline: 1.5421x; 1.0522x over previous
//
#include <hip/hip_runtime.h>

// Warp_Object bicubic warp: B=4, C=3, H=512, W=512, float32.
// Round 10: staging overhaul. (a) TH=8 halves halo amplification (21 staged
// rows / 8 out rows vs 17/4); (b) global_load_lds width=16: HBM->LDS direct,
// no VGPR round-trip, no ds_writes (chunk cc lands at LDS byte 16*cc =
// wave-uniform base + lane*16, exactly the HW pattern); (c) double-buffered
// tile: prefetch plane c+1 during stencil of plane c, 1 barrier per plane.
// 1024 thr/block, 512 blocks = 2 blocks/CU = 32 waves/CU. Coeffs computed
// once, reused across the 3 channel planes (displacement-share quirk).

constexpr int B = 4, C = 3, H = 512, W = 512;
constexpr int HW = H * W;              // 2^18
constexpr int TH = 8;                  // output rows per block
constexpr int HALO_UP = 6, HALO_DN = 7;
constexpr int RS = TH + HALO_UP + HALO_DN;   // 21 staged rows
constexpr int LST = 272;               // staged cols; %32=16 bank rotate
constexpr int CH_ROW = LST / 4;        // 68 f4 chunks per staged row
constexpr int NCHUNK = RS * CH_ROW;    // 1428
constexpr int NPOS = 2;                // positions per thread
constexpr int NT = 1024;               // threads per block
constexpr int NB = B * (H / TH) * 2;   // 512 blocks

typedef float f4 __attribute__((ext_vector_type(4)));
typedef f4 f4u __attribute__((aligned(4)));   // 4B-aligned float4 load

typedef const __attribute__((address_space(1))) void* gas_t;
typedef __attribute__((address_space(3))) void* las_t;

__device__ __forceinline__ void gload_lds16(const float* g, float* l) {
    __builtin_amdgcn_global_load_lds((gas_t)g, (las_t)l, 16, 0, 0);
}

__global__ __launch_bounds__(NT, 8)
void warp_bicubic_dbuf(const float* __restrict__ img,
                       const float* __restrict__ dxp,
                       const float* __restrict__ dyp,
                       float* __restrict__ out)
{
    __shared__ float tile[2][RS * LST];        // 2 x 22,848 B = 45,696 B

    int b   = blockIdx.x;
    int swz = (b & 7) * (NB / 8) + (b >> 3);   // XCD-chunked, bijective (512=8*64)
    int bd   = swz >> 7;                       // displacement batch 0..3
    int band = (swz >> 1) & 63;
    int half = swz & 1;
    int yb   = band * TH;
    int xb   = half * 256;
    int cb   = half ? 248 : 0;                 // first staged image col

    int tid  = threadIdx.x;
    int wave = tid >> 6;                       // 0..15
    int ry   = wave >> 1;                      // row in band 0..7
    int hw   = wave & 1;                       // 128-col subhalf
    int lane = tid & 63;
    int y    = yb + ry;
    int xs   = xb + hw * 128 + lane;           // x = xs + 64p, lanes consecutive
    int pixoff = y * W + xs;

    // ---- issue stage of plane 0 into buf 0 (async HBM->LDS) ----
    {
        const float* plane = img + (size_t)bd * HW;
        for (int cc = tid; cc < NCHUNK; cc += NT) {
            int r  = cc / CH_ROW;
            int c4 = (cc - r * CH_ROW) * 4;
            int scol = min(cb + c4, W - 4);
            int sr   = min(max(yb - HALO_UP + r, 0), H - 1);
            gload_lds16(plane + sr * W + scol, &tile[0][cc * 4]);
        }
    }

    // ---- dx/dy + coefficients (VALU overlaps the staging flight) ----
    float dxa[NPOS], dya[NPOS];
#pragma unroll
    for (int p = 0; p < NPOS; ++p) {
        dxa[p] = __builtin_nontemporal_load(dxp + bd * HW + pixoff + 64 * p);
        dya[p] = __builtin_nontemporal_load(dyp + bd * HW + pixoff + 64 * p);
    }

    float wx[NPOS][4];      // x-weights (image-edge clamp folded)
    float cyw[NPOS][4];     // y-coefficients
    int   lbase[NPOS];      // LDS dword base = relv*LST + lsv
    unsigned relv[NPOS], lsv[NPOS];
    bool  intile[NPOS];
#pragma unroll
    for (int p = 0; p < NPOS; ++p) {
        int x = xs + 64 * p;
        float xm = (float)x + dxa[p];          // == ref up to ~3e-5 px rounding
        float ym = (float)y + dya[p];
        float x0f = floorf(xm), y0f = floorf(ym);
        float tx = xm - x0f, ty = ym - y0f;
        int x0 = (int)x0f, y0 = (int)y0f;
        int s  = min(max(x0 - 1, 0), W - 4);   // 4-wide window start (image cols)

        float tx2 = tx * tx, tx3 = tx2 * tx;
        float cx0 = (-tx3 + 2.0f * tx2 - tx) * 0.5f;
        float cx1 = (3.0f * tx3 - 5.0f * tx2 + 2.0f) * 0.5f;
        float cx2 = (-3.0f * tx3 + 4.0f * tx2 + tx) * 0.5f;
        float cx3 = 1.0f - (cx0 + cx1 + cx2);

        float ty2 = ty * ty, ty3 = ty2 * ty;
        cyw[p][0] = (-ty3 + 2.0f * ty2 - ty) * 0.5f;
        cyw[p][1] = (3.0f * ty3 - 5.0f * ty2 + 2.0f) * 0.5f;
        cyw[p][2] = (-3.0f * ty3 + 4.0f * ty2 + ty) * 0.5f;
        cyw[p][3] = 1.0f - (cyw[p][0] + cyw[p][1] + cyw[p][2]);

        if (__builtin_expect(x0 >= 1 && x0 <= W - 3, 1)) {
            wx[p][0] = cx0; wx[p][1] = cx1; wx[p][2] = cx2; wx[p][3] = cx3;
        } else {                               // fold image-edge taps into window
            float w0 = 0.f, w1 = 0.f, w2 = 0.f, w3 = 0.f;
            const float cxa[4] = {cx0, cx1, cx2, cx3};
#pragma unroll
            for (int o = 0; o < 4; ++o) {
                int xi = min(max(x0 - 1 + o, 0), W - 1);
                int e  = xi - s;               // 0..3 always
                float c = cxa[o];
                w0 += (e == 0) ? c : 0.f;
                w1 += (e == 1) ? c : 0.f;
                w2 += (e == 2) ? c : 0.f;
                w3 += (e == 3) ? c : 0.f;
            }
            wx[p][0] = w0; wx[p][1] = w1; wx[p][2] = w2; wx[p][3] = w3;
        }

        relv[p]  = (unsigned)(y0 - (yb - HALO_UP + 1));  // staged row of y0-1
        lsv[p]   = (unsigned)(s - cb);                   // staged col of window
        intile[p] = (relv[p] <= (unsigned)(RS - 4)) & (lsv[p] <= (unsigned)(LST - 4));
        lbase[p] = (int)relv[p] * LST + (int)lsv[p];
    }

    __syncthreads();   // vmcnt(0)+barrier: plane-0 tile landed

    // ---- plane loop: prefetch next while stenciling current ----
#pragma unroll
    for (int c = 0; c < C; ++c) {
        int nb = c & 1;
        if (c + 1 < C) {                       // async prefetch into other buf
            const float* plane = img + (size_t)(bd + 4 * (c + 1)) * HW;
            for (int cc = tid; cc < NCHUNK; cc += NT) {
                int r  = cc / CH_ROW;
                int c4 = (cc - r * CH_ROW) * 4;
                int scol = min(cb + c4, W - 4);
                int sr   = min(max(yb - HALO_UP + r, 0), H - 1);
                gload_lds16(plane + sr * W + scol, &tile[nb ^ 1][cc * 4]);
            }
        }

        int kp = bd + 4 * c;
        const float* __restrict__ plane = img + (size_t)kp * HW;
        const float* __restrict__ tp = &tile[nb][0];
        float* __restrict__ obase = out + (size_t)kp * HW + pixoff;
#pragma unroll
        for (int p = 0; p < NPOS; ++p) {
            float acc;
            if (__builtin_expect(intile[p], 1)) {
                const float* rp = tp + lbase[p];
                float r0 = cyw[p][0] * (wx[p][0]*rp[0] + wx[p][1]*rp[1] + wx[p][2]*rp[2] + wx[p][3]*rp[3]);
                rp += LST;
                float r1 = cyw[p][1] * (wx[p][0]*rp[0] + wx[p][1]*rp[1] + wx[p][2]*rp[2] + wx[p][3]*rp[3]);
                rp += LST;
                float r2 = cyw[p][2] * (wx[p][0]*rp[0] + wx[p][1]*rp[1] + wx[p][2]*rp[2] + wx[p][3]*rp[3]);
                rp += LST;
                float r3 = cyw[p][3] * (wx[p][0]*rp[0] + wx[p][1]*rp[1] + wx[p][2]*rp[2] + wx[p][3]*rp[3]);
                acc = (r0 + r1) + (r2 + r3);
            } else {
                // rare Gaussian-tail escape: always-correct global path
                int y0 = (int)relv[p] + (yb - HALO_UP + 1);
                int s  = (int)lsv[p] + cb;
                acc = 0.f;
#pragma unroll
                for (int j = 0; j < 4; ++j) {
                    int yi = min(max(y0 - 1 + j, 0), H - 1);
                    f4 v = *(const f4u*)(plane + yi * W + s);
                    acc += cyw[p][j] * (wx[p][0]*v.x + wx[p][1]*v.y + wx[p][2]*v.z + wx[p][3]*v.w);
                }
            }
            __builtin_nontemporal_store(acc, obase + 64 * p);
        }

        if (c + 1 < C) __syncthreads();        // drains prefetch; gates buf reuse
    }
}

extern "C" void kernel_launch(void* const* d_in, const int* in_sizes, int n_in,
                              void* d_out, int out_size, void* d_ws, size_t ws_size,
                              hipStream_t stream) {
    const float* img = (const float*)d_in[0];
    const float* dx  = (const float*)d_in[1];
    const float* dy  = (const float*)d_in[2];
    float* out = (float*)d_out;

    dim3 block(NT);
    dim3 grid(NB);   // 512 blocks -> 2 resident blocks/CU, whole grid co-resident
    hipLaunchKernelGGL(warp_bicubic_dbuf, grid, block, 0, stream,
                       img, dx, dy, out);
}

// Round 11
// 16.611 us; speedup vs baseline: 1.5569x; 1.0096x over previous
//
#include <hip/hip_runtime.h>

// Warp_Object bicubic warp: B=4, C=3, H=512, W=512, float32.
// Round 11: single-barrier kernel. Stage ALL 3 channel planes (they share
// displacement coords -> shared coeffs) into one 65,280B LDS block via
// global_load_lds width=16, issue everything up front, ONE vmcnt(0)+barrier,
// then pure LDS stencil for 3 planes. Output NT stores never barrier-drained.
// RS=20 (halo 6/6) x LST=272 x 3 planes fits under the 64KB static limit;
// 2 blocks/CU = 32 waves/CU. Edge-row Gaussian escapees (P~4e-4) take the
// always-correct global fallback.

constexpr int B = 4, C = 3, H = 512, W = 512;
constexpr int HW = H * W;              // 2^18
constexpr int TH = 8;                  // output rows per block
constexpr int HALO_UP = 6, HALO_DN = 6;
constexpr int RS = TH + HALO_UP + HALO_DN;   // 20 staged rows
constexpr int LST = 272;               // staged cols; %32=16 bank rotate
constexpr int CH_ROW = LST / 4;        // 68 f4 chunks per staged row
constexpr int NCHUNK = RS * CH_ROW;    // 1360 chunks per plane
constexpr int TILE_DW = RS * LST;      // 5440 dwords per plane
constexpr int NPOS = 2;                // positions per thread
constexpr int NT = 1024;               // threads per block
constexpr int NB = B * (H / TH) * 2;   // 512 blocks

typedef float f4 __attribute__((ext_vector_type(4)));
typedef f4 f4u __attribute__((aligned(4)));   // 4B-aligned float4 load

typedef const __attribute__((address_space(1))) void* gas_t;
typedef __attribute__((address_space(3))) void* las_t;

__device__ __forceinline__ void gload_lds16(const float* g, float* l) {
    __builtin_amdgcn_global_load_lds((gas_t)g, (las_t)l, 16, 0, 0);
}

__global__ __launch_bounds__(NT, 8)
void warp_bicubic_1bar(const float* __restrict__ img,
                       const float* __restrict__ dxp,
                       const float* __restrict__ dyp,
                       float* __restrict__ out)
{
    __shared__ float tile[C][TILE_DW];         // 65,280 B -> 2 blocks/CU

    int b   = blockIdx.x;
    int swz = (b & 7) * (NB / 8) + (b >> 3);   // XCD-chunked, bijective (512=8*64)
    int bd   = swz >> 7;                       // displacement batch 0..3
    int band = (swz >> 1) & 63;
    int half = swz & 1;
    int yb   = band * TH;
    int xb   = half * 256;
    int cb   = half ? 248 : 0;                 // first staged image col

    int tid  = threadIdx.x;
    int wave = tid >> 6;                       // 0..15
    int ry   = wave >> 1;                      // row in band 0..7
    int hw   = wave & 1;                       // 128-col subhalf
    int lane = tid & 63;
    int y    = yb + ry;
    int xs   = xb + hw * 128 + lane;           // x = xs + 64p, lanes consecutive
    int pixoff = y * W + xs;

    // ---- issue staging of ALL 3 planes (async HBM->LDS, max MLP) ----
#pragma unroll
    for (int c = 0; c < C; ++c) {
        const float* plane = img + (size_t)(bd + 4 * c) * HW;
        for (int cc = tid; cc < NCHUNK; cc += NT) {
            int r  = cc / CH_ROW;
            int c4 = (cc - r * CH_ROW) * 4;
            int scol = min(cb + c4, W - 4);    // clamp: tail cols never read
            int sr   = min(max(yb - HALO_UP + r, 0), H - 1);  // y clamp-to-edge
            gload_lds16(plane + sr * W + scol, &tile[c][cc * 4]);
        }
    }

    // ---- dx/dy + coefficients (computed once, reused x3 planes) ----
    float dxa[NPOS], dya[NPOS];
#pragma unroll
    for (int p = 0; p < NPOS; ++p) {
        dxa[p] = __builtin_nontemporal_load(dxp + bd * HW + pixoff + 64 * p);
        dya[p] = __builtin_nontemporal_load(dyp + bd * HW + pixoff + 64 * p);
    }

    float wx[NPOS][4];      // x-weights (image-edge clamp folded)
    float cyw[NPOS][4];     // y-coefficients
    int   lbase[NPOS];      // LDS dword base = relv*LST + lsv
    unsigned relv[NPOS], lsv[NPOS];
    bool  intile[NPOS];
#pragma unroll
    for (int p = 0; p < NPOS; ++p) {
        int x = xs + 64 * p;
        float xm = (float)x + dxa[p];          // == ref up to ~3e-5 px rounding
        float ym = (float)y + dya[p];
        float x0f = floorf(xm), y0f = floorf(ym);
        float tx = xm - x0f, ty = ym - y0f;
        int x0 = (int)x0f, y0 = (int)y0f;
        int s  = min(max(x0 - 1, 0), W - 4);   // 4-wide window start (image cols)

        float tx2 = tx * tx, tx3 = tx2 * tx;
        float cx0 = (-tx3 + 2.0f * tx2 - tx) * 0.5f;
        float cx1 = (3.0f * tx3 - 5.0f * tx2 + 2.0f) * 0.5f;
        float cx2 = (-3.0f * tx3 + 4.0f * tx2 + tx) * 0.5f;
        float cx3 = 1.0f - (cx0 + cx1 + cx2);

        float ty2 = ty * ty, ty3 = ty2 * ty;
        cyw[p][0] = (-ty3 + 2.0f * ty2 - ty) * 0.5f;
        cyw[p][1] = (3.0f * ty3 - 5.0f * ty2 + 2.0f) * 0.5f;
        cyw[p][2] = (-3.0f * ty3 + 4.0f * ty2 + ty) * 0.5f;
        cyw[p][3] = 1.0f - (cyw[p][0] + cyw[p][1] + cyw[p][2]);

        if (__builtin_expect(x0 >= 1 && x0 <= W - 3, 1)) {
            wx[p][0] = cx0; wx[p][1] = cx1; wx[p][2] = cx2; wx[p][3] = cx3;
        } else {                               // fold image-edge taps into window
            float w0 = 0.f, w1 = 0.f, w2 = 0.f, w3 = 0.f;
            const float cxa[4] = {cx0, cx1, cx2, cx3};
#pragma unroll
            for (int o = 0; o < 4; ++o) {
                int xi = min(max(x0 - 1 + o, 0), W - 1);
                int e  = xi - s;               // 0..3 always
                float c = cxa[o];
                w0 += (e == 0) ? c : 0.f;
                w1 += (e == 1) ? c : 0.f;
                w2 += (e == 2) ? c : 0.f;
                w3 += (e == 3) ? c : 0.f;
            }
            wx[p][0] = w0; wx[p][1] = w1; wx[p][2] = w2; wx[p][3] = w3;
        }

        relv[p]  = (unsigned)(y0 - (yb - HALO_UP + 1));  // staged row of y0-1
        lsv[p]   = (unsigned)(s - cb);                   // staged col of window
        intile[p] = (relv[p] <= (unsigned)(RS - 4)) & (lsv[p] <= (unsigned)(LST - 4));
        lbase[p] = (int)relv[p] * LST + (int)lsv[p];
    }

    __syncthreads();   // the ONLY barrier: vmcnt(0) drains staging, tiles ready

    // ---- stencil: 3 planes x NPOS positions, pure LDS + FMA + NT store ----
#pragma unroll
    for (int c = 0; c < C; ++c) {
        int kp = bd + 4 * c;
        const float* __restrict__ plane = img + (size_t)kp * HW;
        const float* __restrict__ tp = &tile[c][0];
        float* __restrict__ obase = out + (size_t)kp * HW + pixoff;
#pragma unroll
        for (int p = 0; p < NPOS; ++p) {
            float acc;
            if (__builtin_expect(intile[p], 1)) {
                const float* rp = tp + lbase[p];
                float r0 = cyw[p][0] * (wx[p][0]*rp[0] + wx[p][1]*rp[1] + wx[p][2]*rp[2] + wx[p][3]*rp[3]);
                rp += LST;
                float r1 = cyw[p][1] * (wx[p][0]*rp[0] + wx[p][1]*rp[1] + wx[p][2]*rp[2] + wx[p][3]*rp[3]);
                rp += LST;
                float r2 = cyw[p][2] * (wx[p][0]*rp[0] + wx[p][1]*rp[1] + wx[p][2]*rp[2] + wx[p][3]*rp[3]);
                rp += LST;
                float r3 = cyw[p][3] * (wx[p][0]*rp[0] + wx[p][1]*rp[1] + wx[p][2]*rp[2] + wx[p][3]*rp[3]);
                acc = (r0 + r1) + (r2 + r3);
            } else {
                // rare Gaussian-tail escape: always-correct global path
                int y0 = (int)relv[p] + (yb - HALO_UP + 1);
                int s  = (int)lsv[p] + cb;
                acc = 0.f;
#pragma unroll
                for (int j = 0; j < 4; ++j) {
                    int yi = min(max(y0 - 1 + j, 0), H - 1);
                    f4 v = *(const f4u*)(plane + yi * W + s);
                    acc += cyw[p][j] * (wx[p][0]*v.x + wx[p][1]*v.y + wx[p][2]*v.z + wx[p][3]*v.w);
                }
            }
            __builtin_nontemporal_store(acc, obase + 64 * p);
        }
    }
}

extern "C" void kernel_launch(void* const* d_in, const int* in_sizes, int n_in,
                              void* d_out, int out_size, void* d_ws, size_t ws_size,
                              hipStream_t stream) {
    const float* img = (const float*)d_in[0];
    const float* dx  = (const float*)d_in[1];
    const float* dy  = (const float*)d_in[2];
    float* out = (float*)d_out;

    dim3 block(NT);
    dim3 grid(NB);   // 512 blocks -> 2 resident blocks/CU, whole grid co-resident
    hipLaunchKernelGGL(warp_bicubic_1bar, grid, block, 0, stream,
                       img, dx, dy, out);
}